// Round 1
// baseline (154.935 us; speedup 1.0000x reference)
//
#include <hip/hip_runtime.h>
#include <hip/hip_bf16.h>

// Problem constants (setup_inputs): B=2, N=16384, M=1024, IN=OUT=256
#define NPTS   32768
#define K_DIM  256
#define O_DIM  256
#define M_ATOMS 1024

typedef __attribute__((ext_vector_type(8))) short short8;
typedef __attribute__((ext_vector_type(4))) float f32x4;

__device__ __forceinline__ unsigned short bf16_rn(float f) {
  unsigned u = __float_as_uint(f);
  unsigned r = u + 0x7FFFu + ((u >> 16) & 1u);
  return (unsigned short)(r >> 16);
}

// Kernel 0: split W into bf16 hi/lo pair (65536 elements).
__global__ __launch_bounds__(256) void wconv_kernel(const float* __restrict__ W,
                                                    unsigned short* __restrict__ wh,
                                                    unsigned short* __restrict__ wl) {
  int i = blockIdx.x * 256 + threadIdx.x;
  float w = W[i];
  unsigned short h = bf16_rn(w);
  float hf = __uint_as_float((unsigned)h << 16);
  wh[i] = h;
  wl[i] = bf16_rn(w - hf);
}

// Kernel 1: per-point omega = 30*(1 + clamp(freq_net(q),0,5)*exp(-min_dist)).
// 256 blocks x 256 threads; block handles 128 points, 2 threads/point split atoms.
__global__ __launch_bounds__(256) void omega_kernel(
    const float* __restrict__ qc, const float* __restrict__ atoms,
    const float* __restrict__ fw1, const float* __restrict__ fb1,
    const float* __restrict__ fw2, const float* __restrict__ fb2,
    float* __restrict__ omega) {
  __shared__ float ax[M_ATOMS], ay[M_ATOMS], az[M_ATOMS];
  __shared__ float red[128];
  const int base = blockIdx.x * 128;          // first point of this block
  const int batch = base >> 14;               // 16384 points per batch
  const float* A = atoms + (size_t)batch * M_ATOMS * 3;
  for (int i = threadIdx.x; i < M_ATOMS; i += 256) {
    ax[i] = A[i * 3 + 0];
    ay[i] = A[i * 3 + 1];
    az[i] = A[i * 3 + 2];
  }
  __syncthreads();
  const int p = threadIdx.x & 127;
  const int half = threadIdx.x >> 7;          // waves 0,1 -> 0; waves 2,3 -> 1
  const int pt = base + p;
  const float qx = qc[pt * 3 + 0], qy = qc[pt * 3 + 1], qz = qc[pt * 3 + 2];
  float m0 = 3.0e38f, m1 = 3.0e38f, m2 = 3.0e38f, m3 = 3.0e38f;
  const int i0 = half * (M_ATOMS / 2);
  for (int i = i0; i < i0 + M_ATOMS / 2; i += 4) {
    float dx, dy, dz;
    dx = ax[i + 0] - qx; dy = ay[i + 0] - qy; dz = az[i + 0] - qz;
    m0 = fminf(m0, dx * dx + dy * dy + dz * dz);
    dx = ax[i + 1] - qx; dy = ay[i + 1] - qy; dz = az[i + 1] - qz;
    m1 = fminf(m1, dx * dx + dy * dy + dz * dz);
    dx = ax[i + 2] - qx; dy = ay[i + 2] - qy; dz = az[i + 2] - qz;
    m2 = fminf(m2, dx * dx + dy * dy + dz * dz);
    dx = ax[i + 3] - qx; dy = ay[i + 3] - qy; dz = az[i + 3] - qz;
    m3 = fminf(m3, dx * dx + dy * dy + dz * dz);
  }
  float md = fminf(fminf(m0, m1), fminf(m2, m3));
  if (half) red[p] = md;
  __syncthreads();
  if (!half) {
    md = fminf(md, red[p]);
    float mind = sqrtf(fmaxf(md, 1.0e-4f));   // sqrt/max monotone -> commute with min
    float acc = fb2[0];
#pragma unroll
    for (int j = 0; j < 16; ++j) {
      float z = fw1[j * 3 + 0] * qx + fw1[j * 3 + 1] * qy + fw1[j * 3 + 2] * qz + fb1[j];
      acc += fw2[j] * log1pf(__expf(z));      // softplus
    }
    // clamp [0,5]; fmaxf(NaN,0)=0 matches nan_to_num(clip(...))
    float ls = fminf(fmaxf(acc, 0.0f), 5.0f);
    omega[pt] = 30.0f * (1.0f + ls * __expf(-mind));
  }
}

// Kernel 2: pre = x @ W^T + b via split-bf16 MFMA (hi*hi + hi*lo + lo*hi),
// then out = sin(omega * pre). 256 blocks x 256 threads; wave = 32 points x 256 cols.
__global__ __launch_bounds__(256) void gemm_sin_kernel(
    const float* __restrict__ x, const float* __restrict__ omega,
    const unsigned short* __restrict__ w_hi, const unsigned short* __restrict__ w_lo,
    const float* __restrict__ bias, float* __restrict__ out) {
  const int lane = threadIdx.x & 63;
  const int wave = threadIdx.x >> 6;
  const int lrow = lane & 15;     // A row within tile / B col within tile
  const int lk = lane >> 4;       // k-group (8 k each)
  const int pbase = blockIdx.x * 128 + wave * 32;

  // A fragments: 2 row-tiles x 8 k-chunks, hi+lo bf16, converted from fp32 on the fly.
  short8 ahi[2][8], alo[2][8];
#pragma unroll
  for (int t = 0; t < 2; ++t) {
    const float* xr = x + (size_t)(pbase + t * 16 + lrow) * K_DIM + lk * 8;
#pragma unroll
    for (int kc = 0; kc < 8; ++kc) {
      const f32x4* xv = (const f32x4*)(xr + kc * 32);
      f32x4 f0 = xv[0];
      f32x4 f1 = xv[1];
      short8 h, l;
#pragma unroll
      for (int j = 0; j < 4; ++j) {
        float v0 = f0[j];
        unsigned short h0 = bf16_rn(v0);
        h[j] = (short)h0;
        l[j] = (short)bf16_rn(v0 - __uint_as_float((unsigned)h0 << 16));
        float v1 = f1[j];
        unsigned short h1 = bf16_rn(v1);
        h[j + 4] = (short)h1;
        l[j + 4] = (short)bf16_rn(v1 - __uint_as_float((unsigned)h1 << 16));
      }
      ahi[t][kc] = h;
      alo[t][kc] = l;
    }
  }

  // omega per accumulator row (C/D map: row = (lane>>4)*4 + reg)
  float om[2][4];
#pragma unroll
  for (int t = 0; t < 2; ++t)
#pragma unroll
    for (int j = 0; j < 4; ++j)
      om[t][j] = omega[pbase + t * 16 + lk * 4 + j];

#pragma unroll 1
  for (int c = 0; c < 16; ++c) {
    const unsigned short* wh = w_hi + (size_t)(c * 16 + lrow) * K_DIM + lk * 8;
    const unsigned short* wl = w_lo + (size_t)(c * 16 + lrow) * K_DIM + lk * 8;
    // 6 independent accumulator chains (hi*hi, lo*hi, hi*lo for 2 row-tiles)
    f32x4 aHH0 = {0.f, 0.f, 0.f, 0.f}, aLH0 = {0.f, 0.f, 0.f, 0.f}, aHL0 = {0.f, 0.f, 0.f, 0.f};
    f32x4 aHH1 = {0.f, 0.f, 0.f, 0.f}, aLH1 = {0.f, 0.f, 0.f, 0.f}, aHL1 = {0.f, 0.f, 0.f, 0.f};
#pragma unroll
    for (int kc = 0; kc < 8; ++kc) {
      short8 bh = *(const short8*)(wh + kc * 32);
      short8 bl = *(const short8*)(wl + kc * 32);
      aHH0 = __builtin_amdgcn_mfma_f32_16x16x32_bf16(ahi[0][kc], bh, aHH0, 0, 0, 0);
      aHH1 = __builtin_amdgcn_mfma_f32_16x16x32_bf16(ahi[1][kc], bh, aHH1, 0, 0, 0);
      aLH0 = __builtin_amdgcn_mfma_f32_16x16x32_bf16(alo[0][kc], bh, aLH0, 0, 0, 0);
      aLH1 = __builtin_amdgcn_mfma_f32_16x16x32_bf16(alo[1][kc], bh, aLH1, 0, 0, 0);
      aHL0 = __builtin_amdgcn_mfma_f32_16x16x32_bf16(ahi[0][kc], bl, aHL0, 0, 0, 0);
      aHL1 = __builtin_amdgcn_mfma_f32_16x16x32_bf16(ahi[1][kc], bl, aHL1, 0, 0, 0);
    }
    f32x4 s0 = aHH0 + aLH0 + aHL0;
    f32x4 s1 = aHH1 + aLH1 + aHL1;
    float bv = bias[c * 16 + lrow];
#pragma unroll
    for (int t = 0; t < 2; ++t) {
      f32x4 a = t ? s1 : s0;
#pragma unroll
      for (int j = 0; j < 4; ++j) {
        float pre = a[j] + bv;
        float th = om[t][j] * pre;
        out[(size_t)(pbase + t * 16 + lk * 4 + j) * O_DIM + c * 16 + lrow] = __sinf(th);
      }
    }
  }
}

extern "C" void kernel_launch(void* const* d_in, const int* in_sizes, int n_in,
                              void* d_out, int out_size, void* d_ws, size_t ws_size,
                              hipStream_t stream) {
  const float* x     = (const float*)d_in[0];
  const float* qc    = (const float*)d_in[1];
  const float* atoms = (const float*)d_in[2];
  const float* W     = (const float*)d_in[3];
  const float* b     = (const float*)d_in[4];
  const float* fw1   = (const float*)d_in[5];
  const float* fb1   = (const float*)d_in[6];
  const float* fw2   = (const float*)d_in[7];
  const float* fb2   = (const float*)d_in[8];
  float* out = (float*)d_out;

  // workspace layout: omega[32768] f32 (128 KB) | w_hi[65536] u16 (128 KB) | w_lo[65536] u16 (128 KB)
  float* omega = (float*)d_ws;
  unsigned short* w_hi = (unsigned short*)((char*)d_ws + 32768 * sizeof(float));
  unsigned short* w_lo = w_hi + 65536;

  wconv_kernel<<<256, 256, 0, stream>>>(W, w_hi, w_lo);
  omega_kernel<<<256, 256, 0, stream>>>(qc, atoms, fw1, fb1, fw2, fb2, omega);
  gemm_sin_kernel<<<256, 256, 0, stream>>>(x, omega, w_hi, w_lo, b, out);
}

// Round 2
// 137.237 us; speedup vs baseline: 1.1290x; 1.1290x over previous
//
#include <hip/hip_runtime.h>
#include <hip/hip_bf16.h>

// Problem constants (setup_inputs): B=2, N=16384, M=1024, IN=OUT=256
#define NPTS    32768
#define K_DIM   256
#define O_DIM   256
#define M_ATOMS 1024

typedef __attribute__((ext_vector_type(8))) short short8;
typedef __attribute__((ext_vector_type(4))) float f32x4;

__device__ __forceinline__ unsigned short bf16_rn(float f) {
  unsigned u = __float_as_uint(f);
  unsigned r = u + 0x7FFFu + ((u >> 16) & 1u);
  return (unsigned short)(r >> 16);
}

// Fused prep kernel.
// Blocks [0,512): omega for 64 points each (4 waves split 1024 atoms, 256 each).
// Blocks [512,544): split W into bf16 hi/lo (65536 elems, 8 per thread).
__global__ __launch_bounds__(256) void prep_kernel(
    const float* __restrict__ qc, const float* __restrict__ atoms,
    const float* __restrict__ fw1, const float* __restrict__ fb1,
    const float* __restrict__ fw2, const float* __restrict__ fb2,
    const float* __restrict__ W,
    float* __restrict__ omega, unsigned short* __restrict__ wh,
    unsigned short* __restrict__ wl) {
  __shared__ float4 at[M_ATOMS];     // (x, y, z, |a|^2)
  __shared__ float red[4][64];

  if (blockIdx.x >= 512) {           // ---- W conversion part ----
    int base = (blockIdx.x - 512) * 2048 + threadIdx.x * 8;
    f32x4 f0 = *(const f32x4*)(W + base);
    f32x4 f1 = *(const f32x4*)(W + base + 4);
    short8 h, l;
#pragma unroll
    for (int j = 0; j < 4; ++j) {
      unsigned short h0 = bf16_rn(f0[j]);
      h[j] = (short)h0;
      l[j] = (short)bf16_rn(f0[j] - __uint_as_float((unsigned)h0 << 16));
      unsigned short h1 = bf16_rn(f1[j]);
      h[j + 4] = (short)h1;
      l[j + 4] = (short)bf16_rn(f1[j] - __uint_as_float((unsigned)h1 << 16));
    }
    *(short8*)(wh + base) = h;
    *(short8*)(wl + base) = l;
    return;
  }

  // ---- omega part ----
  const int base = blockIdx.x * 64;
  const int batch = base >> 14;      // 16384 points per batch
  const float* A = atoms + (size_t)batch * M_ATOMS * 3;
  for (int i = threadIdx.x; i < M_ATOMS; i += 256) {
    const float* ap = A + i * 3;
    float ax = ap[0], ay = ap[1], az = ap[2];
    at[i] = make_float4(ax, ay, az, ax * ax + ay * ay + az * az);
  }
  __syncthreads();

  const int lane = threadIdx.x & 63;
  const int w = threadIdx.x >> 6;
  const int pt = base + lane;
  const float qx = qc[pt * 3 + 0], qy = qc[pt * 3 + 1], qz = qc[pt * 3 + 2];

  float m0 = 3.0e38f, m1 = 3.0e38f, m2 = 3.0e38f, m3 = 3.0e38f;
  const int i0 = w * 256;
  for (int i = i0; i < i0 + 256; i += 4) {
    float4 a0 = at[i + 0], a1 = at[i + 1], a2 = at[i + 2], a3 = at[i + 3];
    float d;
    d = a0.x * qx; d = __fmaf_rn(a0.y, qy, d); d = __fmaf_rn(a0.z, qz, d);
    m0 = fminf(m0, __fmaf_rn(d, -2.0f, a0.w));
    d = a1.x * qx; d = __fmaf_rn(a1.y, qy, d); d = __fmaf_rn(a1.z, qz, d);
    m1 = fminf(m1, __fmaf_rn(d, -2.0f, a1.w));
    d = a2.x * qx; d = __fmaf_rn(a2.y, qy, d); d = __fmaf_rn(a2.z, qz, d);
    m2 = fminf(m2, __fmaf_rn(d, -2.0f, a2.w));
    d = a3.x * qx; d = __fmaf_rn(a3.y, qy, d); d = __fmaf_rn(a3.z, qz, d);
    m3 = fminf(m3, __fmaf_rn(d, -2.0f, a3.w));
  }
  float md = fminf(fminf(m0, m1), fminf(m2, m3));
  red[w][lane] = md;
  __syncthreads();
  if (w == 0) {
    md = fminf(md, fminf(fminf(red[1][lane], red[2][lane]), red[3][lane]));
    md += qx * qx + qy * qy + qz * qz;          // |q-a|^2 = |q|^2 - 2q.a + |a|^2
    float mind = sqrtf(fmaxf(md, 1.0e-4f));     // sqrt/max monotone, commute with min
    float acc = fb2[0];
#pragma unroll
    for (int j = 0; j < 16; ++j) {
      float z = fw1[j * 3 + 0] * qx + fw1[j * 3 + 1] * qy + fw1[j * 3 + 2] * qz + fb1[j];
      acc += fw2[j] * log1pf(__expf(z));        // softplus
    }
    float ls = fminf(fmaxf(acc, 0.0f), 5.0f);   // fmaxf(NaN,0)=0 == nan_to_num(clip)
    omega[pt] = 30.0f * (1.0f + ls * __expf(-mind));
  }
}

// GEMM + sin, split-K 2-way. 512 blocks x 256 threads.
// Wave pair (kh=0,1) covers the same 32 points; each wave does half of K.
// K-halves combined via double-buffered LDS exchange; wave kh finalizes
// row-tile kh (16 rows) so store work is balanced.
__global__ __launch_bounds__(256) void gemm_sin_kernel(
    const float* __restrict__ x, const float* __restrict__ omega,
    const unsigned short* __restrict__ w_hi, const unsigned short* __restrict__ w_lo,
    const float* __restrict__ bias, float* __restrict__ out) {
  __shared__ f32x4 xfer[2][4][64];   // [buf][wave][lane], 8 KB
  const int lane = threadIdx.x & 63;
  const int wave = threadIdx.x >> 6;
  const int kh = wave & 1;           // K-half
  const int ptile = wave >> 1;       // which 32-point group in the block
  const int lrow = lane & 15;        // A row / B col within 16x16 tile
  const int lk = lane >> 4;          // k-group (8 k each)
  const int pbase = blockIdx.x * 64 + ptile * 32;

  // A fragments: 2 row-tiles x 4 k-chunks (this wave's K-half), fp32 -> bf16 hi/lo.
  short8 ahi[2][4], alo[2][4];
#pragma unroll
  for (int t = 0; t < 2; ++t) {
    const float* xr = x + (size_t)(pbase + t * 16 + lrow) * K_DIM + kh * 128 + lk * 8;
#pragma unroll
    for (int kc = 0; kc < 4; ++kc) {
      const f32x4* xv = (const f32x4*)(xr + kc * 32);
      f32x4 f0 = xv[0];
      f32x4 f1 = xv[1];
      short8 h, l;
#pragma unroll
      for (int j = 0; j < 4; ++j) {
        unsigned short h0 = bf16_rn(f0[j]);
        h[j] = (short)h0;
        l[j] = (short)bf16_rn(f0[j] - __uint_as_float((unsigned)h0 << 16));
        unsigned short h1 = bf16_rn(f1[j]);
        h[j + 4] = (short)h1;
        l[j + 4] = (short)bf16_rn(f1[j] - __uint_as_float((unsigned)h1 << 16));
      }
      ahi[t][kc] = h;
      alo[t][kc] = l;
    }
  }

  // omega for the row-tile this wave finalizes (tile kh); C/D row = lk*4+j
  float om[4];
#pragma unroll
  for (int j = 0; j < 4; ++j)
    om[j] = omega[pbase + kh * 16 + lk * 4 + j];

#pragma unroll 1
  for (int c = 0; c < 16; ++c) {
    const unsigned short* wh = w_hi + (size_t)(c * 16 + lrow) * K_DIM + kh * 128 + lk * 8;
    const unsigned short* wl = w_lo + (size_t)(c * 16 + lrow) * K_DIM + kh * 128 + lk * 8;
    f32x4 aHH0 = {0.f,0.f,0.f,0.f}, aLH0 = {0.f,0.f,0.f,0.f}, aHL0 = {0.f,0.f,0.f,0.f};
    f32x4 aHH1 = {0.f,0.f,0.f,0.f}, aLH1 = {0.f,0.f,0.f,0.f}, aHL1 = {0.f,0.f,0.f,0.f};
#pragma unroll
    for (int kc = 0; kc < 4; ++kc) {
      short8 bh = *(const short8*)(wh + kc * 32);
      short8 bl = *(const short8*)(wl + kc * 32);
      aHH0 = __builtin_amdgcn_mfma_f32_16x16x32_bf16(ahi[0][kc], bh, aHH0, 0, 0, 0);
      aHH1 = __builtin_amdgcn_mfma_f32_16x16x32_bf16(ahi[1][kc], bh, aHH1, 0, 0, 0);
      aLH0 = __builtin_amdgcn_mfma_f32_16x16x32_bf16(alo[0][kc], bh, aLH0, 0, 0, 0);
      aLH1 = __builtin_amdgcn_mfma_f32_16x16x32_bf16(alo[1][kc], bh, aLH1, 0, 0, 0);
      aHL0 = __builtin_amdgcn_mfma_f32_16x16x32_bf16(ahi[0][kc], bl, aHL0, 0, 0, 0);
      aHL1 = __builtin_amdgcn_mfma_f32_16x16x32_bf16(ahi[1][kc], bl, aHL1, 0, 0, 0);
    }
    f32x4 s0 = aHH0 + aLH0 + aHL0;   // partial (this K-half) for tile 0
    f32x4 s1 = aHH1 + aLH1 + aHL1;   // partial for tile 1

    // Exchange: each wave ships the tile it does NOT finalize to its partner.
    const int buf = c & 1;           // double buffer + single barrier: race-free
    xfer[buf][wave][lane] = kh ? s0 : s1;
    __syncthreads();
    f32x4 part = xfer[buf][wave ^ 1][lane];
    f32x4 tot = (kh ? s1 : s0) + part;

    float bv = bias[c * 16 + lrow];
    float* orow = out + (size_t)(pbase + kh * 16) * O_DIM + c * 16 + lrow;
#pragma unroll
    for (int j = 0; j < 4; ++j) {
      float pre = tot[j] + bv;
      orow[(size_t)(lk * 4 + j) * O_DIM] = __sinf(om[j] * pre);
    }
  }
}

extern "C" void kernel_launch(void* const* d_in, const int* in_sizes, int n_in,
                              void* d_out, int out_size, void* d_ws, size_t ws_size,
                              hipStream_t stream) {
  const float* x     = (const float*)d_in[0];
  const float* qc    = (const float*)d_in[1];
  const float* atoms = (const float*)d_in[2];
  const float* W     = (const float*)d_in[3];
  const float* b     = (const float*)d_in[4];
  const float* fw1   = (const float*)d_in[5];
  const float* fb1   = (const float*)d_in[6];
  const float* fw2   = (const float*)d_in[7];
  const float* fb2   = (const float*)d_in[8];
  float* out = (float*)d_out;

  // workspace: omega[32768] f32 | w_hi[65536] u16 | w_lo[65536] u16
  float* omega = (float*)d_ws;
  unsigned short* w_hi = (unsigned short*)((char*)d_ws + 32768 * sizeof(float));
  unsigned short* w_lo = w_hi + 65536;

  prep_kernel<<<544, 256, 0, stream>>>(qc, atoms, fw1, fb1, fw2, fb2, W,
                                       omega, w_hi, w_lo);
  gemm_sin_kernel<<<512, 256, 0, stream>>>(x, omega, w_hi, w_lo, b, out);
}

// Round 3
// 119.481 us; speedup vs baseline: 1.2967x; 1.1486x over previous
//
#include <hip/hip_runtime.h>
#include <hip/hip_bf16.h>

// Problem constants (setup_inputs): B=2, N=16384, M=1024, IN=OUT=256
#define NPTS    32768
#define K_DIM   256
#define O_DIM   256
#define M_ATOMS 1024

typedef __attribute__((ext_vector_type(8))) short short8;
typedef __attribute__((ext_vector_type(4))) float f32x4;

__device__ __forceinline__ unsigned short bf16_rn(float f) {
  unsigned u = __float_as_uint(f);
  unsigned r = u + 0x7FFFu + ((u >> 16) & 1u);
  return (unsigned short)(r >> 16);
}

__device__ __forceinline__ void cvt8(const f32x4 f0, const f32x4 f1,
                                     short8* h, short8* l) {
#pragma unroll
  for (int j = 0; j < 4; ++j) {
    unsigned short h0 = bf16_rn(f0[j]);
    (*h)[j] = (short)h0;
    (*l)[j] = (short)bf16_rn(f0[j] - __uint_as_float((unsigned)h0 << 16));
    unsigned short h1 = bf16_rn(f1[j]);
    (*h)[j + 4] = (short)h1;
    (*l)[j + 4] = (short)bf16_rn(f1[j] - __uint_as_float((unsigned)h1 << 16));
  }
}

// async global->LDS, 16B per lane; LDS dest = wave-uniform base + lane*16
__device__ __forceinline__ void async16(void* l, const void* g) {
  __builtin_amdgcn_global_load_lds(
      (const __attribute__((address_space(1))) void*)g,
      (__attribute__((address_space(3))) void*)l, 16, 0, 0);
}

// Kernel 0: W -> bf16 hi/lo in MFMA-fragment-major layout [kc8][ct16][lane64][8].
// Fragment map (verified in R1/R2): col = ct*16 + (lane&15), k = kc*32 + (lane>>4)*8 + e.
__global__ __launch_bounds__(256) void wprep_kernel(const float* __restrict__ W,
                                                    unsigned short* __restrict__ whF,
                                                    unsigned short* __restrict__ wlF) {
  int t = blockIdx.x * 256 + threadIdx.x;   // 0..8191
  int lane = t & 63;
  int ct = (t >> 6) & 15;
  int kc = t >> 10;
  int col = ct * 16 + (lane & 15);
  int k0 = kc * 32 + (lane >> 4) * 8;
  const float* src = W + (size_t)col * K_DIM + k0;
  f32x4 f0 = *(const f32x4*)(src);
  f32x4 f1 = *(const f32x4*)(src + 4);
  short8 h, l;
  cvt8(f0, f1, &h, &l);
  *(short8*)(whF + (size_t)t * 8) = h;
  *(short8*)(wlF + (size_t)t * 8) = l;
}

// Fused GEMM + omega + sin. 512 blocks x 256 threads (4 waves x 16 points).
// K-loop: BK=32, 8 iters, B hi/lo staged to LDS (32KB chunks, double-buffered),
// A per-lane from HBM with one-iter-ahead prefetch+convert.
// Epilogue: atoms -> LDS (reuse buffer 0), min-dist (4 lanes/point), freq_net,
// omega, then sin(omega*(acc+bias)) stores.
__global__ __launch_bounds__(256, 2) void fused_kernel(
    const float* __restrict__ x, const float* __restrict__ qc,
    const float* __restrict__ atoms,
    const unsigned short* __restrict__ whF, const unsigned short* __restrict__ wlF,
    const float* __restrict__ bias,
    const float* __restrict__ fw1, const float* __restrict__ fb1,
    const float* __restrict__ fw2, const float* __restrict__ fb2,
    float* __restrict__ out) {
  __shared__ f32x4 bsh[2][2048];            // 2 x 32 KB
  char* ldsC = (char*)&bsh[0][0];
  const int lane = threadIdx.x & 63;
  const int wave = threadIdx.x >> 6;
  const int lrow = lane & 15;
  const int lk = lane >> 4;
  const int pbase = blockIdx.x * 64 + wave * 16;
  const int row = pbase + lrow;

  // bias per output col (lives through the kernel; 16 VGPR)
  float bias_r[16];
#pragma unroll
  for (int ct = 0; ct < 16; ++ct) bias_r[ct] = bias[ct * 16 + lrow];

  const char* whB = (const char*)whF;
  const char* wlB = (const char*)wlF;
  const int toff = wave * 1024 + lane * 16; // per-lane byte offset inside a 16KB chunk

  // stage chunk 0 into buffer 0
  {
    char* db = ldsC;
    const char* gh = whB + toff;
    const char* gl = wlB + toff;
#pragma unroll
    for (int j = 0; j < 4; ++j) {
      async16(db + j * 4096 + wave * 1024, gh + j * 4096);
      async16(db + 16384 + j * 4096 + wave * 1024, gl + j * 4096);
    }
  }

  // A fragment for iter 0
  const float* xr = x + (size_t)row * K_DIM + lk * 8;
  f32x4 a0 = *(const f32x4*)(xr);
  f32x4 a1 = *(const f32x4*)(xr + 4);
  short8 ahi, alo;
  cvt8(a0, a1, &ahi, &alo);

  f32x4 acc[16];
#pragma unroll
  for (int ct = 0; ct < 16; ++ct) acc[ct] = (f32x4){0.f, 0.f, 0.f, 0.f};

  __syncthreads();                          // chunk 0 staged (vmcnt drained)

  int cur = 0;
  f32x4 a0n, a1n;
#pragma unroll 1
  for (int it = 0; it < 8; ++it) {
    if (it < 7) {
      // prefetch next B chunk into the other buffer
      char* db = ldsC + (cur ^ 1) * 32768;
      const char* gh = whB + (it + 1) * 16384 + toff;
      const char* gl = wlB + (it + 1) * 16384 + toff;
#pragma unroll
      for (int j = 0; j < 4; ++j) {
        async16(db + j * 4096 + wave * 1024, gh + j * 4096);
        async16(db + 16384 + j * 4096 + wave * 1024, gl + j * 4096);
      }
      // prefetch next A fragment
      const float* xn = x + (size_t)row * K_DIM + (it + 1) * 32 + lk * 8;
      a0n = *(const f32x4*)(xn);
      a1n = *(const f32x4*)(xn + 4);
    }
    const char* bp = ldsC + cur * 32768;
#pragma unroll
    for (int ct = 0; ct < 16; ++ct) {
      short8 bh = *(const short8*)(bp + ct * 1024 + lane * 16);
      short8 bl = *(const short8*)(bp + 16384 + ct * 1024 + lane * 16);
      acc[ct] = __builtin_amdgcn_mfma_f32_16x16x32_bf16(ahi, bh, acc[ct], 0, 0, 0);
      acc[ct] = __builtin_amdgcn_mfma_f32_16x16x32_bf16(alo, bh, acc[ct], 0, 0, 0);
      acc[ct] = __builtin_amdgcn_mfma_f32_16x16x32_bf16(ahi, bl, acc[ct], 0, 0, 0);
    }
    __syncthreads();                        // next chunk staged & all reads of cur done
    if (it < 7) {
      cvt8(a0n, a1n, &ahi, &alo);           // VALU for next iter, overlaps next ds_reads
      cur ^= 1;
    }
  }

  // ---- omega epilogue: atoms into LDS (reuse buffer 0) ----
  const int batch = pbase >> 14;            // 16384 points per batch; 64 | 16384
  const float* A = atoms + (size_t)batch * M_ATOMS * 3;
  f32x4* at4 = (f32x4*)ldsC;
  for (int i = threadIdx.x; i < M_ATOMS; i += 256) {
    const float* ap = A + i * 3;
    float ax = ap[0], ay = ap[1], az = ap[2];
    f32x4 v = {ax, ay, az, ax * ax + ay * ay + az * az};
    at4[i] = v;
  }
  __syncthreads();

  // 4 lanes per point: point p = lane&15, atom segment = lane>>4
  const int pt = pbase + lrow;
  const float qx = qc[(size_t)pt * 3 + 0];
  const float qy = qc[(size_t)pt * 3 + 1];
  const float qz = qc[(size_t)pt * 3 + 2];
  float m0 = 3.0e38f, m1 = 3.0e38f, m2 = 3.0e38f, m3 = 3.0e38f;
  const int i0 = lk * 256;
  for (int i = i0; i < i0 + 256; i += 4) {
    f32x4 v0 = at4[i + 0], v1 = at4[i + 1], v2 = at4[i + 2], v3 = at4[i + 3];
    float d;
    d = v0[0] * qx; d = __fmaf_rn(v0[1], qy, d); d = __fmaf_rn(v0[2], qz, d);
    m0 = fminf(m0, __fmaf_rn(d, -2.0f, v0[3]));
    d = v1[0] * qx; d = __fmaf_rn(v1[1], qy, d); d = __fmaf_rn(v1[2], qz, d);
    m1 = fminf(m1, __fmaf_rn(d, -2.0f, v1[3]));
    d = v2[0] * qx; d = __fmaf_rn(v2[1], qy, d); d = __fmaf_rn(v2[2], qz, d);
    m2 = fminf(m2, __fmaf_rn(d, -2.0f, v2[3]));
    d = v3[0] * qx; d = __fmaf_rn(v3[1], qy, d); d = __fmaf_rn(v3[2], qz, d);
    m3 = fminf(m3, __fmaf_rn(d, -2.0f, v3[3]));
  }
  float md = fminf(fminf(m0, m1), fminf(m2, m3));
  md = fminf(md, __shfl_xor(md, 16));       // reduce across the 4 atom segments
  md = fminf(md, __shfl_xor(md, 32));
  md += qx * qx + qy * qy + qz * qz;        // |q-a|^2 = |q|^2 - 2 q.a + |a|^2
  float mind = sqrtf(fmaxf(md, 1.0e-4f));   // sqrt/max monotone -> commute with min

  float facc = fb2[0];
#pragma unroll
  for (int j = 0; j < 16; ++j) {
    float z = fw1[j * 3 + 0] * qx + fw1[j * 3 + 1] * qy + fw1[j * 3 + 2] * qz + fb1[j];
    facc += fw2[j] * log1pf(__expf(z));     // softplus
  }
  float ls = fminf(fmaxf(facc, 0.0f), 5.0f); // fmaxf(NaN,0)=0 == nan_to_num(clip)
  float omega_l = 30.0f * (1.0f + ls * __expf(-mind));

  // redistribute: accumulator row r = lk*4+j needs omega of point r (held by lane r)
  float om[4];
#pragma unroll
  for (int j = 0; j < 4; ++j) om[j] = __shfl(omega_l, lk * 4 + j);

  // ---- store: out[pt, col] = sin(omega * (acc + bias)) ----
#pragma unroll
  for (int ct = 0; ct < 16; ++ct) {
#pragma unroll
    for (int j = 0; j < 4; ++j) {
      float pre = acc[ct][j] + bias_r[ct];
      out[(size_t)(pbase + lk * 4 + j) * O_DIM + ct * 16 + lrow] = __sinf(om[j] * pre);
    }
  }
}

extern "C" void kernel_launch(void* const* d_in, const int* in_sizes, int n_in,
                              void* d_out, int out_size, void* d_ws, size_t ws_size,
                              hipStream_t stream) {
  (void)in_sizes; (void)n_in; (void)out_size; (void)ws_size;
  const float* x     = (const float*)d_in[0];
  const float* qc    = (const float*)d_in[1];
  const float* atoms = (const float*)d_in[2];
  const float* W     = (const float*)d_in[3];
  const float* b     = (const float*)d_in[4];
  const float* fw1   = (const float*)d_in[5];
  const float* fb1   = (const float*)d_in[6];
  const float* fw2   = (const float*)d_in[7];
  const float* fb2   = (const float*)d_in[8];
  float* out = (float*)d_out;

  // workspace: whF[65536] u16 (128 KB) | wlF[65536] u16 (128 KB)
  unsigned short* whF = (unsigned short*)d_ws;
  unsigned short* wlF = whF + 65536;

  wprep_kernel<<<32, 256, 0, stream>>>(W, whF, wlF);
  fused_kernel<<<512, 256, 0, stream>>>(x, qc, atoms, whF, wlF, b,
                                        fw1, fb1, fw2, fb2, out);
}